// Round 8
// baseline (460.196 us; speedup 1.0000x reference)
//
#include <hip/hip_runtime.h>
#include <math.h>

typedef float f32x4 __attribute__((ext_vector_type(4)));

#define SGSHIFT 12    // src-group: 4096 nodes -> G,K,V rows = 3MB (L2-resident)
#define DBSHIFT 8     // dst-bucket: 256 nodes -> G,Q rows = 128KB hot run
#define MAXKEY 4096   // >= (13 src-groups << 8) | 255
#define UNROLL 8

// R7 evidence: XCD-chunking did nothing (FETCH 408=408) -> src side already
// near-compulsory (~40MB); dominant fetch is dst-side ~360MB (512MB logical,
// ~30% hit). Fix: composite sort (src-group, dst-bucket) so each (group,
// bucket) tile's ~200 distinct dst rows are fetched once while hot.
// Time ~ TCC bytes @ ~4.1 TB/s across all rounds -> bytes are the lever.

__global__ void zero_kernel(int* p, int n) {
    int i = blockIdx.x * blockDim.x + threadIdx.x;
    if (i < n) p[i] = 0;
}

__global__ __launch_bounds__(256) void hist_kernel(
    const int* __restrict__ src, const int* __restrict__ dst, int nE, int nkey,
    int* __restrict__ counts)
{
    __shared__ int lc[MAXKEY];
    for (int i = threadIdx.x; i < nkey; i += blockDim.x) lc[i] = 0;
    __syncthreads();
    for (int e = blockIdx.x * blockDim.x + threadIdx.x; e < nE;
         e += gridDim.x * blockDim.x) {
        int key = ((src[e] >> SGSHIFT) << 8) | (dst[e] >> DBSHIFT);
        atomicAdd(&lc[key], 1);
    }
    __syncthreads();
    for (int i = threadIdx.x; i < nkey; i += blockDim.x) {
        int c = lc[i];
        if (c) atomicAdd(&counts[i], c);
    }
}

// exclusive scan of counts[nkey] -> cursor, one block of 256 threads,
// 16 contiguous entries per thread + block scan of per-thread sums.
__global__ __launch_bounds__(256) void scan_kernel(
    const int* __restrict__ counts, int nkey, int* __restrict__ cursor)
{
    __shared__ int buf[256];
    const int t = threadIdx.x;
    const int per = (MAXKEY / 256);   // 16
    int s = 0;
    #pragma unroll
    for (int j = 0; j < per; j++) {
        int idx = t * per + j;
        if (idx < nkey) s += counts[idx];
    }
    buf[t] = s;
    __syncthreads();
    #pragma unroll
    for (int off = 1; off < 256; off <<= 1) {
        int x = (t >= off) ? buf[t - off] : 0;
        __syncthreads();
        buf[t] += x;
        __syncthreads();
    }
    int running = buf[t] - s;   // exclusive prefix of this thread's slice
    #pragma unroll
    for (int j = 0; j < per; j++) {
        int idx = t * per + j;
        if (idx < nkey) { cursor[idx] = running; running += counts[idx]; }
    }
}

// block-aggregated scatter on composite key; one global atomic per
// (key,chunk) with nonzero count. Records: int2{src|dst<<16, orig_e}.
__global__ __launch_bounds__(256) void scatter_kernel(
    const int* __restrict__ src, const int* __restrict__ dst, int nE, int nkey,
    int* __restrict__ cursor, int2* __restrict__ eidx)
{
    __shared__ int lc[MAXKEY];
    __shared__ int lb[MAXKEY];
    const int chunkSize = blockDim.x * UNROLL;
    for (int chunk = blockIdx.x * chunkSize; chunk < nE;
         chunk += gridDim.x * chunkSize) {
        for (int i = threadIdx.x; i < nkey; i += blockDim.x) lc[i] = 0;
        __syncthreads();
        int myk[UNROLL], myoff[UNROLL], pack[UNROLL];
        #pragma unroll
        for (int u = 0; u < UNROLL; u++) {
            int e = chunk + u * blockDim.x + threadIdx.x;
            if (e < nE) {
                int s = src[e], d = dst[e];
                pack[u] = s | (d << 16);               // s,d < 65536
                myk[u] = ((s >> SGSHIFT) << 8) | (d >> DBSHIFT);
                myoff[u] = atomicAdd(&lc[myk[u]], 1);
            } else myk[u] = -1;
        }
        __syncthreads();
        for (int i = threadIdx.x; i < nkey; i += blockDim.x) {
            int c = lc[i];
            lb[i] = c ? atomicAdd(&cursor[i], c) : 0;
        }
        __syncthreads();
        #pragma unroll
        for (int u = 0; u < UNROLL; u++) {
            if (myk[u] >= 0) {
                int pos = lb[myk[u]] + myoff[u];
                int e = chunk + u * blockDim.x + threadIdx.x;
                eidx[pos] = make_int2(pack[u], e);
            }
        }
        __syncthreads();
    }
}

// main: identical structure to R7 — contiguous sorted range per block,
// ranges swizzled so each XCD covers a contiguous eighth (keeps each
// src-group's 3MB resident in ~1 L2). 16 lanes/edge, 16 slots/block.
__global__ __launch_bounds__(256) void edge_message_kernel(
    const float* __restrict__ G,
    const float* __restrict__ K,
    const float* __restrict__ Q,
    const float* __restrict__ V,
    const int2* __restrict__ eidx,
    float* __restrict__ out,
    int nE)
{
    const int tid  = threadIdx.x;
    const int slot = tid >> 4;
    const int sub  = tid & 15;

    const int nx = gridDim.x >> 3;
    const int chunkIdx = (blockIdx.x & 7) * nx + (blockIdx.x >> 3);
    const int perBlock = (nE + gridDim.x - 1) / gridDim.x;
    const int start = chunkIdx * perBlock;
    const int end   = min(start + perBlock, nE);

    const f32x4* __restrict__ G4 = (const f32x4*)G;
    const f32x4* __restrict__ K4 = (const f32x4*)K;
    const f32x4* __restrict__ Q4 = (const f32x4*)Q;
    const f32x4* __restrict__ V4 = (const f32x4*)V;
    f32x4* __restrict__ out4 = (f32x4*)out;

    const float inv_sqrt_d = 0.125f;

    for (int i0 = start; i0 < end; i0 += 16) {
        const int i = i0 + slot;
        const bool valid = (i < end);
        const int ic = valid ? i : (end - 1);

        const int2 rec = eidx[ic];
        const unsigned u = (unsigned)rec.x;
        const int s = (int)(u & 0xFFFFu);
        const int d = (int)(u >> 16);
        const int o = rec.y;

        const f32x4 gs = G4[s * 16 + sub];
        const f32x4 gd = G4[d * 16 + sub];
        const f32x4 ks = K4[s * 16 + sub];
        const f32x4 qd = Q4[d * 16 + sub];
        const f32x4 vs = V4[s * 16 + sub];

        const f32x4 df = gs - gd;
        const f32x4 kq = ks * qd;
        float a = df.x * df.x + df.y * df.y + df.z * df.z + df.w * df.w;
        float b = kq.x + kq.y + kq.z + kq.w;

        #pragma unroll
        for (int off = 8; off > 0; off >>= 1) {
            a += __shfl_xor(a, off, 64);
            b += __shfl_xor(b, off, 64);
        }

        float t1 = -sqrtf(a + 1e-6f) * inv_sqrt_d;
        t1 = fminf(fmaxf(t1, -5.0f), 5.0f);
        float t2 = b * inv_sqrt_d;
        t2 = fminf(fmaxf(t2, -5.0f), 5.0f);
        const float w = __expf(t1 + t2);

        if (valid) {
            __builtin_nontemporal_store(w * vs, &out4[(size_t)o * 16 + sub]);
        }
    }
}

extern "C" void kernel_launch(void* const* d_in, const int* in_sizes, int n_in,
                              void* d_out, int out_size, void* d_ws, size_t ws_size,
                              hipStream_t stream)
{
    const float* G   = (const float*)d_in[0];
    const float* K   = (const float*)d_in[1];
    const float* Q   = (const float*)d_in[2];
    const float* V   = (const float*)d_in[3];
    const int*   src = (const int*)d_in[4];
    const int*   dst = (const int*)d_in[5];
    float* out = (float*)d_out;

    const int nE = in_sizes[4];
    const int nNodes = in_sizes[0] / 64;
    const int nkey = ((((nNodes - 1) >> SGSHIFT) + 1) << 8);   // 13<<8 = 3328

    // workspace: counts[MAXKEY] | cursor[MAXKEY] | eidx[nE]
    int* counts = (int*)d_ws;
    int* cursor = counts + MAXKEY;
    int2* eidx  = (int2*)(counts + 2 * MAXKEY);

    zero_kernel<<<(nkey + 255) / 256, 256, 0, stream>>>(counts, nkey);
    hist_kernel<<<256, 256, 0, stream>>>(src, dst, nE, nkey, counts);
    scan_kernel<<<1, 256, 0, stream>>>(counts, nkey, cursor);
    {
        const int chunk = 256 * UNROLL;
        int grid = (nE + chunk - 1) / chunk;
        scatter_kernel<<<grid, 256, 0, stream>>>(src, dst, nE, nkey, cursor, eidx);
    }
    {
        int grid = 2048;   // multiple of 8 for XCD chunking
        edge_message_kernel<<<grid, 256, 0, stream>>>(G, K, Q, V, eidx, out, nE);
    }
}